// Round 6
// baseline (1380.258 us; speedup 1.0000x reference)
//
#include <hip/hip_runtime.h>
#include <stdint.h>

// GraphSAGE fused layer, MI355X (gfx950). All tensors fp32.
// N=16384, D=64, adj = binary fp32 mask (1.074 GB), avg degree ~32.
// R5 insight: wave-per-row scan plateaus at ~4 TB/s; the harness fill kernel
// does 6.3 TB/s on the same memory with a flat dense front. So: two-phase.
//   Phase A: fill-pattern grid-stride scan of adj -> per-row column buckets
//            in d_ws (one atomicAdd per nonzero chunk). Dense moving front.
//   Phase B: one wave per row: gather X rows via bucket, GEMV, ReLU, L2-norm.

#define NROWS   16384
#define DDIM    64
#define MAXNNZ  256            // deg ~ Binom(16384, 32/16384): mean 32, sigma 5.7
#define SCAN_BLOCKS 8192
#define CHUNKS  ((size_t)NROWS * NROWS / 4)   // 67,108,864 16-B chunks

typedef uint32_t u32x4 __attribute__((ext_vector_type(4)));

// ---------- Phase 0: zero the per-row counters (d_ws is poisoned 0xAA) ----------
__global__ __launch_bounds__(256) void zero_cnt(int* __restrict__ cnt) {
    cnt[blockIdx.x * 256 + threadIdx.x] = 0;
}

// ---------- Phase A: dense-front scan of adj ----------
__device__ __forceinline__ void process_chunk(u32x4 vv, size_t ci,
                                              int* __restrict__ cnt,
                                              int* __restrict__ bucket) {
    if (vv.x | vv.y | vv.z | vv.w) {              // fp32 0.0f == all-zero bits
        const int e    = (int)(ci << 2);          // flat element idx (<2^28)
        const int row  = e >> 14;
        const int cb   = e & 16383;
        const int nz   = (vv.x ? 1 : 0) + (vv.y ? 1 : 0) + (vv.z ? 1 : 0) + (vv.w ? 1 : 0);
        int p = atomicAdd(&cnt[row], nz);         // one atomic per nonzero chunk
        int* bp = bucket + (size_t)row * MAXNNZ;
        if (vv.x) { if (p < MAXNNZ) bp[p] = cb + 0; ++p; }
        if (vv.y) { if (p < MAXNNZ) bp[p] = cb + 1; ++p; }
        if (vv.z) { if (p < MAXNNZ) bp[p] = cb + 2; ++p; }
        if (vv.w) { if (p < MAXNNZ) bp[p] = cb + 3; ++p; }
    }
}

__global__ __launch_bounds__(256) void scan_adj(const float* __restrict__ adj,
                                                int* __restrict__ cnt,
                                                int* __restrict__ bucket) {
    const size_t T   = (size_t)SCAN_BLOCKS * 256;           // 2,097,152 threads
    const size_t tid = (size_t)blockIdx.x * 256 + threadIdx.x;
    const u32x4* p   = reinterpret_cast<const u32x4*>(adj);
    // CHUNKS == 32*T exactly: 8 iterations x 4 independent loads, no remainder.
#pragma unroll 1
    for (size_t base = tid; base < CHUNKS; base += 4 * T) {
        const u32x4 c0 = __builtin_nontemporal_load(&p[base]);
        const u32x4 c1 = __builtin_nontemporal_load(&p[base + T]);
        const u32x4 c2 = __builtin_nontemporal_load(&p[base + 2 * T]);
        const u32x4 c3 = __builtin_nontemporal_load(&p[base + 3 * T]);
        process_chunk(c0, base,         cnt, bucket);
        process_chunk(c1, base + T,     cnt, bucket);
        process_chunk(c2, base + 2 * T, cnt, bucket);
        process_chunk(c3, base + 3 * T, cnt, bucket);
    }
}

// ---------- Phase B: per-row gather + GEMV + ReLU + L2-normalize ----------
__global__ __launch_bounds__(256, 4) void sage_agg(
    const float* __restrict__ X,      // (N, 64)
    const int*   __restrict__ cnt,    // (N,)
    const int*   __restrict__ bucket, // (N, MAXNNZ)
    const float* __restrict__ W,      // (128, 64) row-major, cache-hot
    const float* __restrict__ bias,   // (64,)
    float* __restrict__ out)          // (N, 64)
{
    __shared__ float scat[4][2 * DDIM];

    const int tid  = threadIdx.x;
    const int lane = tid & 63;
    const int w    = tid >> 6;
    const int row  = blockIdx.x * 4 + w;      // one wave per row

    const float bv  = bias[lane];
    const int   nnz = cnt[row];               // lane-uniform, L2-hot
    const int   cn  = (nnz < MAXNNZ) ? nnz : MAXNNZ;
    const int*  bp  = bucket + (size_t)row * MAXNNZ;

    float acc = 0.0f;
    int k = 0;
    for (; k + 4 <= cn; k += 4) {
        const int j0 = bp[k], j1 = bp[k + 1], j2 = bp[k + 2], j3 = bp[k + 3];
        const float a0 = X[(size_t)j0 * DDIM + lane];
        const float a1 = X[(size_t)j1 * DDIM + lane];
        const float a2 = X[(size_t)j2 * DDIM + lane];
        const float a3 = X[(size_t)j3 * DDIM + lane];
        acc += (a0 + a1) + (a2 + a3);
    }
    for (; k < cn; ++k) acc += X[(size_t)bp[k] * DDIM + lane];

    const float xi = X[(size_t)row * DDIM + lane];
    const float h  = (acc + xi) / ((float)nnz + 1.0f);   // deg = rowsum+1 >= 1
    scat[w][lane]        = xi;
    scat[w][DDIM + lane] = h;
    __builtin_amdgcn_wave_barrier();

    float z0 = bv, z1 = 0.0f, z2 = 0.0f, z3 = 0.0f;
#pragma unroll 8
    for (int kk = 0; kk < 2 * DDIM; kk += 4) {
        z0 = fmaf(scat[w][kk + 0], W[(kk + 0) * DDIM + lane], z0);
        z1 = fmaf(scat[w][kk + 1], W[(kk + 1) * DDIM + lane], z1);
        z2 = fmaf(scat[w][kk + 2], W[(kk + 2) * DDIM + lane], z2);
        z3 = fmaf(scat[w][kk + 3], W[(kk + 3) * DDIM + lane], z3);
    }
    float z = (z0 + z1) + (z2 + z3);
    z = fmaxf(z, 0.0f);

    float s2 = z * z;
#pragma unroll
    for (int off = 32; off >= 1; off >>= 1) s2 += __shfl_xor(s2, off);
    const float inv = 1.0f / fmaxf(sqrtf(s2), 1e-12f);
    out[(size_t)row * DDIM + lane] = z * inv;
}

extern "C" void kernel_launch(void* const* d_in, const int* in_sizes, int n_in,
                              void* d_out, int out_size, void* d_ws, size_t ws_size,
                              hipStream_t stream) {
    const float* X   = (const float*)d_in[0];
    const float* adj = (const float*)d_in[1];
    const float* W   = (const float*)d_in[2];
    const float* b   = (const float*)d_in[3];
    float* out = (float*)d_out;

    int* cnt    = (int*)d_ws;                          // 64 KB
    int* bucket = (int*)((char*)d_ws + (64 << 10));    // 16 MB

    zero_cnt<<<NROWS / 256, 256, 0, stream>>>(cnt);
    scan_adj<<<SCAN_BLOCKS, 256, 0, stream>>>(adj, cnt, bucket);
    sage_agg<<<NROWS / 4, 256, 0, stream>>>(X, cnt, bucket, W, b, out);
}

// Round 7
// 1334.195 us; speedup vs baseline: 1.0345x; 1.0345x over previous
//
#include <hip/hip_runtime.h>
#include <stdint.h>

// GraphSAGE fused layer, MI355X (gfx950). All tensors fp32.
// N=16384, D=64, adj = binary fp32 mask (1.074 GB), avg deg ~32.
// R6 lesson: flat dense-front scan (3.46 TB/s) is NOT faster than scattered
// wave-per-row (4.0 TB/s) — access-pattern theory dead. R7 A/B: drop the
// nontemporal hint (present in every slow scan since R4) and go to 1-KB
// granular stagger + depth-8 pipeline. Fused, LDS-only, no __syncthreads.
// One wave per row: 4096 blocks x 4 waves.

#define NROWS   16384
#define DDIM    64
#define MAXNNZ  256       // deg ~ Binom(16384, 32/16384): mean 32, sigma 5.7
#define NBLOCKS 4096
#define PIPE    8         // outstanding 16-B loads per lane (8 KB/wave)

typedef uint32_t u32x4 __attribute__((ext_vector_type(4)));

__global__ __launch_bounds__(256, 4) void sage_fused(
    const float* __restrict__ X,     // (N, 64)
    const float* __restrict__ adj,   // (N, N)
    const float* __restrict__ W,     // (128, 64) row-major, cache-hot
    const float* __restrict__ bias,  // (64,)
    float* __restrict__ out)         // (N, 64)
{
    __shared__ int   slist[4][MAXNNZ];   // per-wave nonzero column list
    __shared__ int   scnt[4];
    __shared__ float scat[4][2 * DDIM];  // per-wave [x_i | h_neigh]

    const int tid  = threadIdx.x;
    const int lane = tid & 63;
    const int w    = tid >> 6;
    const int row  = blockIdx.x * 4 + w;     // one wave per row

    const float bv = bias[lane];

    if (lane == 0) scnt[w] = 0;
    __builtin_amdgcn_wave_barrier();

    // ---- Scan the 64 KB adj row as 64 chunks of 1 KB (u32x4 per lane).
    // Per-row staggered start (1-KB granularity) decorrelates the global
    // address set across the 64-KB power-of-2 row stride. PLAIN cached loads.
    const int start = (row * 37 + (row >> 6) * 13) & 63;
    const u32x4* rowp = reinterpret_cast<const u32x4*>(adj + (size_t)row * NROWS);

    u32x4 buf[PIPE];
#pragma unroll
    for (int i = 0; i < PIPE; ++i)
        buf[i] = rowp[((start + i) & 63) * 64 + lane];

#pragma unroll 1
    for (int so = 0; so < 64; so += PIPE) {
#pragma unroll
        for (int i = 0; i < PIPE; ++i) {
            const int s  = so + i;
            const int ss = (start + s) & 63;          // chunk being processed
            const u32x4 vv = buf[i];
            if (vv.x | vv.y | vv.z | vv.w) {          // fp32 0.0f == all-zero bits
                const int base = (ss * 64 + lane) * 4;
                const uint32_t w4[4] = { vv.x, vv.y, vv.z, vv.w };
#pragma unroll
                for (int j = 0; j < 4; ++j) {
                    if (w4[j]) {
                        const int p = atomicAdd(&scnt[w], 1);
                        if (p < MAXNNZ) slist[w][p] = base + j;
                    }
                }
            }
            if (so + PIPE < 64) {                     // refill with chunk s+PIPE
                const int sn = (start + s + PIPE) & 63;
                buf[i] = rowp[sn * 64 + lane];
            }
        }
    }
    __builtin_amdgcn_wave_barrier();

    const int nnz = scnt[w];               // DS ops in-order within the wave
    const int cn  = (nnz < MAXNNZ) ? nnz : MAXNNZ;

    // ---- Gather-accumulate neighbor X rows (256 B coalesced reads, LLC-hot).
    float acc = 0.0f;
    int k = 0;
    for (; k + 4 <= cn; k += 4) {
        const int j0 = slist[w][k], j1 = slist[w][k + 1];
        const int j2 = slist[w][k + 2], j3 = slist[w][k + 3];
        const float a0 = X[(size_t)j0 * DDIM + lane];
        const float a1 = X[(size_t)j1 * DDIM + lane];
        const float a2 = X[(size_t)j2 * DDIM + lane];
        const float a3 = X[(size_t)j3 * DDIM + lane];
        acc += (a0 + a1) + (a2 + a3);
    }
    for (; k < cn; ++k) acc += X[(size_t)slist[w][k] * DDIM + lane];

    const float xi = X[(size_t)row * DDIM + lane];
    const float h  = (acc + xi) / ((float)nnz + 1.0f);   // deg = rowsum+1 >= 1
    scat[w][lane]        = xi;
    scat[w][DDIM + lane] = h;
    __builtin_amdgcn_wave_barrier();

    // ---- GEMV: z[d] = b[d] + sum_k cat[k] * W[k][d]; W is L1/L2-hot.
    float z0 = bv, z1 = 0.0f, z2 = 0.0f, z3 = 0.0f;
#pragma unroll 8
    for (int kk = 0; kk < 2 * DDIM; kk += 4) {
        z0 = fmaf(scat[w][kk + 0], W[(kk + 0) * DDIM + lane], z0);
        z1 = fmaf(scat[w][kk + 1], W[(kk + 1) * DDIM + lane], z1);
        z2 = fmaf(scat[w][kk + 2], W[(kk + 2) * DDIM + lane], z2);
        z3 = fmaf(scat[w][kk + 3], W[(kk + 3) * DDIM + lane], z3);
    }
    float z = (z0 + z1) + (z2 + z3);
    z = fmaxf(z, 0.0f);

    // ---- Row L2-norm over the 64 lanes, normalize, store.
    float s2 = z * z;
#pragma unroll
    for (int off = 32; off >= 1; off >>= 1) s2 += __shfl_xor(s2, off);
    const float inv = 1.0f / fmaxf(sqrtf(s2), 1e-12f);
    out[(size_t)row * DDIM + lane] = z * inv;
}

extern "C" void kernel_launch(void* const* d_in, const int* in_sizes, int n_in,
                              void* d_out, int out_size, void* d_ws, size_t ws_size,
                              hipStream_t stream) {
    const float* X   = (const float*)d_in[0];
    const float* adj = (const float*)d_in[1];
    const float* W   = (const float*)d_in[2];
    const float* b   = (const float*)d_in[3];
    float* out = (float*)d_out;
    sage_fused<<<NBLOCKS, 256, 0, stream>>>(X, adj, W, b, out);
}